// Round 2
// baseline (118.698 us; speedup 1.0000x reference)
//
#include <hip/hip_runtime.h>

constexpr int NN  = 64;
constexpr int STR = 68;   // padded stride (multiple of 4 for b128 alignment)

// acc(4x4 tile at ib,jb) = Asrc * Bsrc   (both 64x64, row-major, stride STR)
__device__ __forceinline__ void mm64_tile(const float* Asrc, const float* Bsrc,
                                          int ib, int jb, float acc[4][4]) {
    #pragma unroll
    for (int ii = 0; ii < 4; ++ii)
        #pragma unroll
        for (int jj = 0; jj < 4; ++jj) acc[ii][jj] = 0.0f;
    #pragma unroll
    for (int n4 = 0; n4 < 16; ++n4) {
        float a[4][4], b[4][4];
        #pragma unroll
        for (int ii = 0; ii < 4; ++ii)
            *(float4*)a[ii] = *(const float4*)&Asrc[(4 * ib + ii) * STR + 4 * n4];
        #pragma unroll
        for (int c = 0; c < 4; ++c)
            *(float4*)b[c] = *(const float4*)&Bsrc[(4 * n4 + c) * STR + 4 * jb];
        #pragma unroll
        for (int ii = 0; ii < 4; ++ii)
            #pragma unroll
            for (int c = 0; c < 4; ++c)
                #pragma unroll
                for (int jj = 0; jj < 4; ++jj)
                    acc[ii][jj] = fmaf(a[ii][c], b[c][jj], acc[ii][jj]);
    }
}

// acc(ib,jb) = Asrc * Bsrc^T : acc[ii][jj] = sum_n A[4ib+ii][n] * B[4jb+jj][n]
__device__ __forceinline__ void mm64_abt_tile(const float* Asrc, const float* Bsrc,
                                              int ib, int jb, float acc[4][4]) {
    #pragma unroll
    for (int ii = 0; ii < 4; ++ii)
        #pragma unroll
        for (int jj = 0; jj < 4; ++jj) acc[ii][jj] = 0.0f;
    #pragma unroll
    for (int n4 = 0; n4 < 16; ++n4) {
        float a[4][4], b[4][4];
        #pragma unroll
        for (int ii = 0; ii < 4; ++ii)
            *(float4*)a[ii] = *(const float4*)&Asrc[(4 * ib + ii) * STR + 4 * n4];
        #pragma unroll
        for (int jj = 0; jj < 4; ++jj)
            *(float4*)b[jj] = *(const float4*)&Bsrc[(4 * jb + jj) * STR + 4 * n4];
        #pragma unroll
        for (int ii = 0; ii < 4; ++ii)
            #pragma unroll
            for (int jj = 0; jj < 4; ++jj)
                #pragma unroll
                for (int c = 0; c < 4; ++c)
                    acc[ii][jj] = fmaf(a[ii][c], b[jj][c], acc[ii][jj]);
    }
}

// Krylov doubling: Xt rows [k, 2k) <- M * (Xt rows [0,k))^T, i.e.
// Xt[k+j][m] = sum_n M[m][n] * Xt[j][n].  Wave `wid` handles j = wid, wid+4, ...
__device__ __forceinline__ void double_rows(const float* M, float* Xt, int k,
                                            int wid, int lane) {
    if (wid < k) {
        float f[64];
        #pragma unroll
        for (int m4 = 0; m4 < 16; ++m4) {
            float4 r = *(const float4*)&M[lane * STR + 4 * m4];
            f[4 * m4 + 0] = r.x; f[4 * m4 + 1] = r.y;
            f[4 * m4 + 2] = r.z; f[4 * m4 + 3] = r.w;
        }
        for (int j = wid; j < k; j += 4) {
            float a0 = 0, a1 = 0, a2 = 0, a3 = 0;
            #pragma unroll
            for (int m4 = 0; m4 < 16; ++m4) {
                float4 x = *(const float4*)&Xt[j * STR + 4 * m4];
                a0 = fmaf(f[4 * m4 + 0], x.x, a0);
                a1 = fmaf(f[4 * m4 + 1], x.y, a1);
                a2 = fmaf(f[4 * m4 + 2], x.z, a2);
                a3 = fmaf(f[4 * m4 + 3], x.w, a3);
            }
            Xt[(k + j) * STR + lane] = (a0 + a1) + (a2 + a3);
        }
    }
}

__launch_bounds__(256)
__global__ void krylov_kernel(const float* __restrict__ A,
                              const float* __restrict__ Bv,
                              const float* __restrict__ Cv,
                              const float* __restrict__ logdt,
                              float* __restrict__ out)
{
    const int h    = blockIdx.x;
    const int tid  = threadIdx.x;
    const int ib   = tid >> 4;   // 0..15 row-block
    const int jb   = tid & 15;   // 0..15 col-block
    const int lane = tid & 63;
    const int wid  = tid >> 6;

    __shared__ __align__(16) float S1[NN * STR];   // dA / squaring ping
    __shared__ __align__(16) float S2[NN * STR];   // squaring pong / W = E^T
    __shared__ __align__(16) float Vt[NN * STR];   // Vt[r][n] = v_r[n] = (dA^r dB)[n]
    __shared__ __align__(16) float Ut[NN * STR];   // Ut[q][n] = u_q[n] = ((E^T)^q C)[n]
    __shared__ __align__(16) float prow[2][NN];
    __shared__ __align__(16) float fcol[2][NN];
    __shared__ __align__(16) float Bl[NN];

    const float dt = expf(logdt[h]);
    const float cc = 0.5f * dt;

    if (tid < NN) Bl[tid] = Bv[h * NN + tid];

    // ---- build M = I - (dt/2)A into register 4x4 tiles ----
    float T[4][4];
    const float* Ah = A + (size_t)h * NN * NN;
    #pragma unroll
    for (int ii = 0; ii < 4; ++ii) {
        const int gi = 4 * ib + ii;
        float4 a4 = *(const float4*)(Ah + gi * NN + 4 * jb);
        T[ii][0] = (gi == 4 * jb + 0 ? 1.0f : 0.0f) - cc * a4.x;
        T[ii][1] = (gi == 4 * jb + 1 ? 1.0f : 0.0f) - cc * a4.y;
        T[ii][2] = (gi == 4 * jb + 2 ? 1.0f : 0.0f) - cc * a4.z;
        T[ii][3] = (gi == 4 * jb + 3 ? 1.0f : 0.0f) - cc * a4.w;
    }

    // ---- in-place Gauss-Jordan inversion (verified in R1) ----
    for (int kb = 0; kb < 16; ++kb) {
        #pragma unroll
        for (int kk = 0; kk < 4; ++kk) {
            const int k  = 4 * kb + kk;
            const int pb = k & 1;
            if (ib == kb) {
                float4 pv = make_float4(T[kk][0], T[kk][1], T[kk][2], T[kk][3]);
                *(float4*)&prow[pb][4 * jb] = pv;
            }
            if (jb == kb) {
                fcol[pb][4 * ib + 0] = T[0][kk];
                fcol[pb][4 * ib + 1] = T[1][kk];
                fcol[pb][4 * ib + 2] = T[2][kk];
                fcol[pb][4 * ib + 3] = T[3][kk];
            }
            __syncthreads();
            float fc[4], pr[4];
            *(float4*)fc = *(const float4*)&fcol[pb][4 * ib];
            *(float4*)pr = *(const float4*)&prow[pb][4 * jb];
            const float p  = prow[pb][k];
            const float ip = 1.0f / p;
            float pj[4];
            #pragma unroll
            for (int jj = 0; jj < 4; ++jj) pj[jj] = pr[jj] * ip;
            const bool rb_ = (ib == kb), cb_ = (jb == kb);
            #pragma unroll
            for (int ii = 0; ii < 4; ++ii) {
                #pragma unroll
                for (int jj = 0; jj < 4; ++jj) {
                    const bool rowk = rb_ && (ii == kk);
                    const bool colk = cb_ && (jj == kk);
                    float g = T[ii][jj] - fc[ii] * pj[jj];
                    T[ii][jj] = rowk ? (colk ? ip : pj[jj])
                                     : (colk ? -fc[ii] * ip : g);
                }
            }
        }
    }
    // T = Inv = (I - dt/2 A)^-1

    // ---- dA = 2*Inv - I  -> S1 ----
    #pragma unroll
    for (int ii = 0; ii < 4; ++ii) {
        const int gi = 4 * ib + ii;
        float4 d4;
        d4.x = 2.0f * T[ii][0] - (gi == 4 * jb + 0 ? 1.0f : 0.0f);
        d4.y = 2.0f * T[ii][1] - (gi == 4 * jb + 1 ? 1.0f : 0.0f);
        d4.z = 2.0f * T[ii][2] - (gi == 4 * jb + 2 ? 1.0f : 0.0f);
        d4.w = 2.0f * T[ii][3] - (gi == 4 * jb + 3 ? 1.0f : 0.0f);
        *(float4*)&S1[gi * STR + 4 * jb] = d4;
    }
    __syncthreads();

    // ---- seeds: Vt[0] = dB = (dt/2)(dA*B + B), Ut[0] = C ----
    if (tid < 64) {
        float acc = 0.0f;
        #pragma unroll
        for (int m4 = 0; m4 < 16; ++m4) {
            float4 r = *(const float4*)&S1[tid * STR + 4 * m4];
            float4 b = *(const float4*)&Bl[4 * m4];
            acc += r.x * b.x + r.y * b.y + r.z * b.z + r.w * b.w;
        }
        Vt[0 * STR + tid] = cc * (acc + Bl[tid]);
    } else if (tid < 128) {
        Ut[0 * STR + (tid - 64)] = Cv[h * NN + (tid - 64)];
    }
    __syncthreads();

    // ---- ladder A: squarings dA -> dA^64, interleaved V-doubling ----
    // phase s: cur = dA^(2^s); square cur->nxt; Vt rows [2^s, 2^(s+1)) = cur * Vt[0..2^s)
    for (int s = 0; s < 6; ++s) {
        const float* cur = (s & 1) ? S2 : S1;
        float*       nxt = (s & 1) ? S1 : S2;
        float acc[4][4];
        mm64_tile(cur, cur, ib, jb, acc);
        #pragma unroll
        for (int ii = 0; ii < 4; ++ii)
            *(float4*)&nxt[(4 * ib + ii) * STR + 4 * jb] = *(float4*)acc[ii];
        double_rows(cur, Vt, 1 << s, wid, lane);
        __syncthreads();
    }
    // E = dA^64 in S1; Vt rows 0..63 complete

    // ---- transpose: W = E^T -> S2 ----
    #pragma unroll
    for (int ii = 0; ii < 4; ++ii)
        #pragma unroll
        for (int jj = 0; jj < 4; ++jj)
            S2[(4 * ib + ii) * STR + 4 * jb + jj] = S1[(4 * jb + jj) * STR + 4 * ib + ii];
    __syncthreads();

    // ---- ladder B: squarings W -> W^32, interleaved U-doubling ----
    for (int s = 0; s < 6; ++s) {
        const float* cur = (s & 1) ? S1 : S2;
        float*       nxt = (s & 1) ? S2 : S1;
        if (s < 5) {
            float acc[4][4];
            mm64_tile(cur, cur, ib, jb, acc);
            #pragma unroll
            for (int ii = 0; ii < 4; ++ii)
                *(float4*)&nxt[(4 * ib + ii) * STR + 4 * jb] = *(float4*)acc[ii];
        }
        double_rows(cur, Ut, 1 << s, wid, lane);
        __syncthreads();
    }
    // Ut rows 0..63 complete

    // ---- final: Y[q][r] = sum_n Ut[q][n] * Vt[r][n];  out[h][64q + r] ----
    float acc[4][4];
    mm64_abt_tile(Ut, Vt, ib, jb, acc);
    float* oh = out + (size_t)h * 4096;
    #pragma unroll
    for (int ii = 0; ii < 4; ++ii)
        *(float4*)(oh + (4 * ib + ii) * 64 + 4 * jb) = *(float4*)acc[ii];
}

extern "C" void kernel_launch(void* const* d_in, const int* in_sizes, int n_in,
                              void* d_out, int out_size, void* d_ws, size_t ws_size,
                              hipStream_t stream) {
    const float* A  = (const float*)d_in[0];
    const float* B  = (const float*)d_in[1];
    const float* C  = (const float*)d_in[2];
    const float* ld = (const float*)d_in[3];
    float* out = (float*)d_out;
    const int H = in_sizes[3];   // 256 heads
    krylov_kernel<<<H, 256, 0, stream>>>(A, B, C, ld, out);
}

// Round 3
// 93.475 us; speedup vs baseline: 1.2698x; 1.2698x over previous
//
#include <hip/hip_runtime.h>

constexpr int STRU = 68;   // row stride in u32 (272 B, 16B-aligned rows)

typedef short v8s __attribute__((ext_vector_type(8)));
typedef float v4f __attribute__((ext_vector_type(4)));

// fp32 -> packed (bf16_hi << 16) | bf16_lo, both RNE
__device__ __forceinline__ unsigned packhl(float x) {
    unsigned xb = __builtin_bit_cast(unsigned, x);
    unsigned t  = xb + 0x7fffu + ((xb >> 16) & 1u);
    unsigned hi = t & 0xffff0000u;
    float lof = x - __builtin_bit_cast(float, hi);
    unsigned lb = __builtin_bit_cast(unsigned, lof);
    unsigned lo = (lb + 0x7fffu + ((lb >> 16) & 1u)) >> 16;
    return hi | lo;
}

__device__ __forceinline__ float unpackf(unsigned v) {
    float h = __builtin_bit_cast(float, v & 0xffff0000u);
    float l = __builtin_bit_cast(float, v << 16);
    return h + l;
}

// load 8 packed u32 (one MFMA k-fragment of a row) -> hi/lo bf16x8
__device__ __forceinline__ void load_frag(const unsigned* p, v8s& hi, v8s& lo) {
    uint4 a = *(const uint4*)p;
    uint4 b = *(const uint4*)(p + 4);
    uint4 hw, lw;
    hw.x = __builtin_amdgcn_perm(a.y, a.x, 0x07060302u);
    hw.y = __builtin_amdgcn_perm(a.w, a.z, 0x07060302u);
    hw.z = __builtin_amdgcn_perm(b.y, b.x, 0x07060302u);
    hw.w = __builtin_amdgcn_perm(b.w, b.z, 0x07060302u);
    lw.x = __builtin_amdgcn_perm(a.y, a.x, 0x05040100u);
    lw.y = __builtin_amdgcn_perm(a.w, a.z, 0x05040100u);
    lw.z = __builtin_amdgcn_perm(b.y, b.x, 0x05040100u);
    lw.w = __builtin_amdgcn_perm(b.w, b.z, 0x05040100u);
    hi = __builtin_bit_cast(v8s, hw);
    lo = __builtin_bit_cast(v8s, lw);
}

#define MFMA __builtin_amdgcn_mfma_f32_16x16x32_bf16

// D = P * Q^T (64x64, packed LDS operands). MODE 0: store packed to D.
// MODE 1: +I on diagonal, store packed. MODE 2: store fp32 to G (row-major 64).
template<int MODE>
__device__ __forceinline__ void mm64(const unsigned* P, const unsigned* Q,
                                     unsigned* D, float* G, int tid) {
    const int lane = tid & 63, w = tid >> 6;
    const int nh = lane & 15, qh = lane >> 4;
    const int tr0 = (w >> 1) << 1, tc0 = (w & 1) << 1;   // 2x2 tile block per wave
    v4f acc[2][2] = {};
    #pragma unroll
    for (int kk = 0; kk < 2; ++kk) {
        const int kc = kk * 32 + qh * 8;
        v8s ph[2], pl[2], qhf[2], qlf[2];
        #pragma unroll
        for (int r = 0; r < 2; ++r)
            load_frag(P + ((tr0 + r) * 16 + nh) * STRU + kc, ph[r], pl[r]);
        #pragma unroll
        for (int c = 0; c < 2; ++c)
            load_frag(Q + ((tc0 + c) * 16 + nh) * STRU + kc, qhf[c], qlf[c]);
        #pragma unroll
        for (int r = 0; r < 2; ++r)
            #pragma unroll
            for (int c = 0; c < 2; ++c) {
                acc[r][c] = MFMA(ph[r], qhf[c], acc[r][c], 0, 0, 0);
                acc[r][c] = MFMA(ph[r], qlf[c], acc[r][c], 0, 0, 0);
                acc[r][c] = MFMA(pl[r], qhf[c], acc[r][c], 0, 0, 0);
            }
    }
    #pragma unroll
    for (int r = 0; r < 2; ++r)
        #pragma unroll
        for (int c = 0; c < 2; ++c) {
            const int col = (tc0 + c) * 16 + nh;
            #pragma unroll
            for (int e = 0; e < 4; ++e) {
                const int row = (tr0 + r) * 16 + qh * 4 + e;
                float v = acc[r][c][e];
                if constexpr (MODE == 1) { if (row == col) v += 1.0f; }
                if constexpr (MODE == 2) G[row * 64 + col] = v;
                else                     D[row * STRU + col] = packhl(v);
            }
        }
}

// Krylov doubling: Xt rows [k,2k) = rows j<k of (Xt[0..16t) * M^T); benign
// garbage in P rows >= k only feeds masked-out output rows.
__device__ __forceinline__ void dbl64(unsigned* Xt, const unsigned* M, int k, int tid) {
    const int lane = tid & 63, w = tid >> 6;
    const int nh = lane & 15, qh = lane >> 4;
    const int tiles = (k + 15) >> 4;
    for (int t = 0; t < tiles; ++t) {
        v4f acc = {};
        #pragma unroll
        for (int kk = 0; kk < 2; ++kk) {
            const int kc = kk * 32 + qh * 8;
            v8s ph, pl, qhf, qlf;
            load_frag(Xt + (t * 16 + nh) * STRU + kc, ph, pl);
            load_frag(M + (w * 16 + nh) * STRU + kc, qhf, qlf);
            acc = MFMA(ph, qhf, acc, 0, 0, 0);
            acc = MFMA(ph, qlf, acc, 0, 0, 0);
            acc = MFMA(pl, qhf, acc, 0, 0, 0);
        }
        #pragma unroll
        for (int e = 0; e < 4; ++e) {
            const int j = t * 16 + qh * 4 + e;
            if (j < k) Xt[(k + j) * STRU + w * 16 + nh] = packhl(acc[e]);
        }
    }
}

__launch_bounds__(256)
__global__ void krylov_kernel(const float* __restrict__ A,
                              const float* __restrict__ Bv,
                              const float* __restrict__ Cv,
                              const float* __restrict__ logdt,
                              float* __restrict__ out)
{
    const int h    = blockIdx.x;
    const int tid  = threadIdx.x;
    const int lane = tid & 63;
    const int w    = tid >> 6;

    // 6 packed 64x64 matrices. 0:S/X 1:NegS2/Dt/SH/N 2:T0,T2/XT 3:T1,T3/NT 4:Vt 5:Ut
    __shared__ __align__(16) unsigned SM[6][64 * STRU];
    __shared__ float Bl[64], Cl[64], t1s[64], t2s[64];

    const float dt = expf(logdt[h]);
    const float c  = 0.5f * dt;
    const float al = 1.0f + 0.5f * c;
    const float sd = -(c * c) / (al * al);      // D~ = sd * (S S^T)
    const float c1 = 2.0f / al;                 // dA = c1*T + c2*SH - I
    const float c2 = 2.0f * c / (al * al);
    const float k1 = dt / al;                   // dB = k1*(T B) + k2*(SH B)
    const float k2 = dt * c / (al * al);

    const float* Ah = A + (size_t)h * 4096;

    // ---- P0: S = A + 0.5 I (exactly antisymmetric), load B, C ----
    for (int idx = tid; idx < 4096; idx += 256) {
        const int r = idx >> 6, cc = idx & 63;
        float v = Ah[idx] + (r == cc ? 0.5f : 0.0f);
        SM[0][r * STRU + cc] = packhl(v);
    }
    if (tid < 64) Bl[tid] = Bv[h * 64 + tid];
    else if (tid < 128) Cl[tid - 64] = Cv[h * 64 + tid - 64];
    __syncthreads();

    // ---- P1: NegS2 = S*S^T = -S^2  (PSD, symmetric) ----
    mm64<0>(SM[0], SM[0], SM[1], nullptr, tid);
    __syncthreads();

    // ---- P2: D~ = sd*NegS2 (in place); T0 = I + D~ ----
    for (int idx = tid; idx < 4096; idx += 256) {
        const int r = idx >> 6, cc = idx & 63;
        const int ad = r * STRU + cc;
        float dv = sd * unpackf(SM[1][ad]);
        SM[1][ad] = packhl(dv);
        SM[2][ad] = packhl(dv + (r == cc ? 1.0f : 0.0f));
    }
    __syncthreads();

    // ---- Horner: T = I + D~ + .. + D~^4  (all symmetric, commuting) ----
    mm64<1>(SM[1], SM[2], SM[3], nullptr, tid);  __syncthreads();  // T1
    mm64<1>(SM[1], SM[3], SM[2], nullptr, tid);  __syncthreads();  // T2
    mm64<1>(SM[1], SM[2], SM[3], nullptr, tid);  __syncthreads();  // T3 = T in SM3
    // ---- SH = S * T  (T symmetric) ----
    mm64<0>(SM[0], SM[3], SM[1], nullptr, tid);  __syncthreads();  // SH in SM1

    // ---- matvecs t1 = T*B, t2 = SH*B; Ut[0] = C ----
    if (w == 0) {
        const unsigned* Tr = SM[3] + lane * STRU;
        float acc = 0.0f;
        #pragma unroll
        for (int m4 = 0; m4 < 16; ++m4) {
            uint4 tv = *(const uint4*)(Tr + 4 * m4);
            acc += unpackf(tv.x) * Bl[4 * m4 + 0] + unpackf(tv.y) * Bl[4 * m4 + 1]
                 + unpackf(tv.z) * Bl[4 * m4 + 2] + unpackf(tv.w) * Bl[4 * m4 + 3];
        }
        t1s[lane] = acc;
    } else if (w == 1) {
        const unsigned* Tr = SM[1] + lane * STRU;
        float acc = 0.0f;
        #pragma unroll
        for (int m4 = 0; m4 < 16; ++m4) {
            uint4 tv = *(const uint4*)(Tr + 4 * m4);
            acc += unpackf(tv.x) * Bl[4 * m4 + 0] + unpackf(tv.y) * Bl[4 * m4 + 1]
                 + unpackf(tv.z) * Bl[4 * m4 + 2] + unpackf(tv.w) * Bl[4 * m4 + 3];
        }
        t2s[lane] = acc;
    } else if (w == 2) {
        SM[5][lane] = packhl(Cl[lane]);          // Ut row 0
    }
    __syncthreads();

    // ---- X = dA = c1*T + c2*SH - I ; XT = dA^T = c1*T - c2*SH - I ----
    // ((S*T)^T = -S*T since T = poly(S^2) commutes with S)
    for (int idx = tid; idx < 4096; idx += 256) {
        const int r = idx >> 6, cc = idx & 63;
        const int ad = r * STRU + cc;
        float tX = unpackf(SM[3][ad]);
        float sh = unpackf(SM[1][ad]);
        float dg = (r == cc) ? 1.0f : 0.0f;
        SM[0][ad] = packhl(c1 * tX + c2 * sh - dg);
        SM[2][ad] = packhl(c1 * tX - c2 * sh - dg);
    }
    if (tid < 64) SM[4][tid] = packhl(k1 * t1s[tid] + k2 * t2s[tid]);  // Vt row 0 = dB
    __syncthreads();

    // ---- ladder A: s=0..5: V-double with X = dA^(2^s); dual squaring ----
    int iX = 0, iXT = 2, iN = 1, iNT = 3;
    for (int s = 0; s < 6; ++s) {
        mm64<0>(SM[iX],  SM[iXT], SM[iN],  nullptr, tid);   // X^2
        mm64<0>(SM[iXT], SM[iX],  SM[iNT], nullptr, tid);   // (X^2)^T
        dbl64(SM[4], SM[iX], 1 << s, tid);                  // Vt rows [2^s, 2^{s+1})
        __syncthreads();
        int t0 = iX;  iX  = iN;  iN  = t0;
        t0 = iXT; iXT = iNT; iNT = t0;
    }
    // now X = dA^64 = E, XT = E^T

    // ---- ladder B: s=0..5: U-double with XT = (E^T)^(2^s); dual squaring ----
    for (int s = 0; s < 6; ++s) {
        dbl64(SM[5], SM[iXT], 1 << s, tid);                 // Ut rows [2^s, 2^{s+1})
        if (s < 5) {
            mm64<0>(SM[iX],  SM[iXT], SM[iN],  nullptr, tid);
            mm64<0>(SM[iXT], SM[iX],  SM[iNT], nullptr, tid);
        }
        __syncthreads();
        if (s < 5) {
            int t0 = iX;  iX  = iN;  iN  = t0;
            t0 = iXT; iXT = iNT; iNT = t0;
        }
    }

    // ---- final: out[h][64q + r] = sum_n Ut[q][n] * Vt[r][n] ----
    mm64<2>(SM[5], SM[4], nullptr, out + (size_t)h * 4096, tid);
}

extern "C" void kernel_launch(void* const* d_in, const int* in_sizes, int n_in,
                              void* d_out, int out_size, void* d_ws, size_t ws_size,
                              hipStream_t stream) {
    const float* A  = (const float*)d_in[0];
    const float* B  = (const float*)d_in[1];
    const float* C  = (const float*)d_in[2];
    const float* ld = (const float*)d_in[3];
    float* out = (float*)d_out;
    const int H = in_sizes[3];   // 256 heads
    krylov_kernel<<<H, 256, 0, stream>>>(A, B, C, ld, out);
}

// Round 4
// 79.633 us; speedup vs baseline: 1.4906x; 1.1738x over previous
//
#include <hip/hip_runtime.h>

constexpr int STRU = 68;   // row stride in u32 (272 B; rows 16B-aligned)

typedef short v8s __attribute__((ext_vector_type(8)));
typedef float v4f __attribute__((ext_vector_type(4)));

// fp32 -> packed (bf16_hi << 16) | bf16_lo. hi = truncated, lo = Dekker remainder
// rounded half-up. Reconstruction error ~2^-17 relative.
__device__ __forceinline__ unsigned packhl(float x) {
    unsigned xb = __builtin_bit_cast(unsigned, x);
    unsigned hb = xb & 0xffff0000u;
    float lof = x - __builtin_bit_cast(float, hb);           // exact
    unsigned lb = __builtin_bit_cast(unsigned, lof) + 0x8000u;
    return __builtin_amdgcn_perm(xb, lb, 0x07060302u);       // [hi16(xb) | hi16(lb)]
}

__device__ __forceinline__ float unpackf(unsigned v) {
    float h = __builtin_bit_cast(float, v & 0xffff0000u);
    float l = __builtin_bit_cast(float, v << 16);
    return h + l;
}

// load 8 packed u32 (one MFMA k-fragment of a row) -> hi/lo bf16x8
__device__ __forceinline__ void load_frag(const unsigned* p, v8s& hi, v8s& lo) {
    uint4 a = *(const uint4*)p;
    uint4 b = *(const uint4*)(p + 4);
    uint4 hw, lw;
    hw.x = __builtin_amdgcn_perm(a.y, a.x, 0x07060302u);
    hw.y = __builtin_amdgcn_perm(a.w, a.z, 0x07060302u);
    hw.z = __builtin_amdgcn_perm(b.y, b.x, 0x07060302u);
    hw.w = __builtin_amdgcn_perm(b.w, b.z, 0x07060302u);
    lw.x = __builtin_amdgcn_perm(a.y, a.x, 0x05040100u);
    lw.y = __builtin_amdgcn_perm(a.w, a.z, 0x05040100u);
    lw.z = __builtin_amdgcn_perm(b.y, b.x, 0x05040100u);
    lw.w = __builtin_amdgcn_perm(b.w, b.z, 0x05040100u);
    hi = __builtin_bit_cast(v8s, hw);
    lo = __builtin_bit_cast(v8s, lw);
}

#define MFMA __builtin_amdgcn_mfma_f32_16x16x32_bf16

// D = P * Q^T (64x64, packed LDS operands), 8 waves, 2 tiles/wave.
// MODE 0: packed->D. 1: +I, packed->D. 2: fp32->G (global, row stride 64).
// MODE 3: packed->D AND transposed packed->DT (b128 per tile).
// MODE 4: ca*v -> D; ca*v + I -> DT  (both normal orientation).
// MODE 5: t=unpack(R[row][col]); ca*t - I + cb*v -> D; ca*t - I - cb*v -> DT.
template<int MODE>
__device__ __forceinline__ void mm64(const unsigned* __restrict__ P,
                                     const unsigned* __restrict__ Q,
                                     unsigned* D, unsigned* DT, float* G,
                                     const unsigned* R, float ca, float cb,
                                     int tid) {
    const int lane = tid & 63, w = tid >> 6;
    const int nh = lane & 15, qh = lane >> 4;
    const int tr = w >> 1, tc0 = (w & 1) << 1;   // wave: tiles (tr,tc0),(tr,tc0+1)
    v4f acc[2] = {v4f{0,0,0,0}, v4f{0,0,0,0}};
    #pragma unroll
    for (int kk = 0; kk < 2; ++kk) {
        const int kc = kk * 32 + qh * 8;
        v8s ph, pl, q0h, q0l, q1h, q1l;
        load_frag(P + (tr * 16 + nh) * STRU + kc, ph, pl);
        load_frag(Q + (tc0 * 16 + nh) * STRU + kc, q0h, q0l);
        load_frag(Q + ((tc0 + 1) * 16 + nh) * STRU + kc, q1h, q1l);
        acc[0] = MFMA(ph, q0h, acc[0], 0, 0, 0);
        acc[0] = MFMA(ph, q0l, acc[0], 0, 0, 0);
        acc[0] = MFMA(pl, q0h, acc[0], 0, 0, 0);
        acc[1] = MFMA(ph, q1h, acc[1], 0, 0, 0);
        acc[1] = MFMA(ph, q1l, acc[1], 0, 0, 0);
        acc[1] = MFMA(pl, q1h, acc[1], 0, 0, 0);
    }
    const int row0 = tr * 16 + qh * 4;
    #pragma unroll
    for (int c = 0; c < 2; ++c) {
        const int col = (tc0 + c) * 16 + nh;
        if constexpr (MODE == 2) {
            #pragma unroll
            for (int e = 0; e < 4; ++e) G[(row0 + e) * 64 + col] = acc[c][e];
        } else if constexpr (MODE == 0) {
            #pragma unroll
            for (int e = 0; e < 4; ++e)
                D[(row0 + e) * STRU + col] = packhl(acc[c][e]);
        } else if constexpr (MODE == 1) {
            #pragma unroll
            for (int e = 0; e < 4; ++e) {
                float v = acc[c][e] + ((row0 + e) == col ? 1.0f : 0.0f);
                D[(row0 + e) * STRU + col] = packhl(v);
            }
        } else if constexpr (MODE == 3) {
            uint4 tp;
            #pragma unroll
            for (int e = 0; e < 4; ++e) {
                unsigned pk = packhl(acc[c][e]);
                D[(row0 + e) * STRU + col] = pk;
                ((unsigned*)&tp)[e] = pk;
            }
            *(uint4*)&DT[col * STRU + row0] = tp;   // DT[col][row0..row0+3]
        } else if constexpr (MODE == 4) {
            #pragma unroll
            for (int e = 0; e < 4; ++e) {
                float dv = ca * acc[c][e];
                float dg = ((row0 + e) == col) ? 1.0f : 0.0f;
                D[(row0 + e) * STRU + col]  = packhl(dv);
                DT[(row0 + e) * STRU + col] = packhl(dv + dg);
            }
        } else if constexpr (MODE == 5) {
            #pragma unroll
            for (int e = 0; e < 4; ++e) {
                float t  = unpackf(R[(row0 + e) * STRU + col]);
                float dg = ((row0 + e) == col) ? 1.0f : 0.0f;
                float base = ca * t - dg;
                float sv   = cb * acc[c][e];
                D[(row0 + e) * STRU + col]  = packhl(base + sv);
                DT[(row0 + e) * STRU + col] = packhl(base - sv);
            }
        }
    }
}

// Krylov doubling: Xt rows [k,2k) <- (rows j<k of Xt) * M^T.
// Garbage in source rows >= k only feeds discarded output rows (MFMA row m of D
// depends only on row m of A-operand). 8 waves: unit = (row tile, col block).
__device__ __forceinline__ void dbl64(unsigned* Xt, const unsigned* M, int k, int tid) {
    const int lane = tid & 63, w = tid >> 6;
    const int nh = lane & 15, qh = lane >> 4;
    const int nt = (k + 15) >> 4;
    if (w < 4 * nt) {
        const int t = w >> 2, cb = w & 3;
        v4f acc = {0, 0, 0, 0};
        #pragma unroll
        for (int kk = 0; kk < 2; ++kk) {
            const int kc = kk * 32 + qh * 8;
            v8s ph, pl, mh, ml;
            load_frag(Xt + (t * 16 + nh) * STRU + kc, ph, pl);
            load_frag(M + (cb * 16 + nh) * STRU + kc, mh, ml);
            acc = MFMA(ph, mh, acc, 0, 0, 0);
            acc = MFMA(ph, ml, acc, 0, 0, 0);
            acc = MFMA(pl, mh, acc, 0, 0, 0);
        }
        #pragma unroll
        for (int e = 0; e < 4; ++e) {
            const int j = t * 16 + qh * 4 + e;
            if (j < k) Xt[(k + j) * STRU + cb * 16 + nh] = packhl(acc[e]);
        }
    }
}

__launch_bounds__(512)
__global__ void krylov_kernel(const float* __restrict__ A,
                              const float* __restrict__ Bv,
                              const float* __restrict__ Cv,
                              const float* __restrict__ logdt,
                              float* __restrict__ out)
{
    const int h    = blockIdx.x;
    const int tid  = threadIdx.x;
    const int lane = tid & 63;
    const int w    = tid >> 6;

    __shared__ __align__(16) unsigned SM[6][64 * STRU];
    __shared__ float Bl[64];

    const float dt = expf(logdt[h]);
    const float c  = 0.5f * dt;
    const float al = 1.0f + 0.5f * c;
    const float sd = -(c * c) / (al * al);   // D~ = sd * (S S^T)
    const float c1 = 2.0f / al;              // X = c1*T + c2*SH - I
    const float c2 = 2.0f * c / (al * al);

    const float* Ah = A + (size_t)h * 4096;

    // ---- P0: pack S = A + 0.5I into SM0; B -> Bl; Ut row0 = C -> SM5 ----
    for (int idx = tid; idx < 1024; idx += 512) {
        const int r = idx >> 4, c0 = (idx & 15) * 4;
        float4 v = *(const float4*)(Ah + idx * 4);
        if (r == c0 + 0) v.x += 0.5f;
        if (r == c0 + 1) v.y += 0.5f;
        if (r == c0 + 2) v.z += 0.5f;
        if (r == c0 + 3) v.w += 0.5f;
        uint4 pk = make_uint4(packhl(v.x), packhl(v.y), packhl(v.z), packhl(v.w));
        *(uint4*)&SM[0][r * STRU + c0] = pk;
    }
    if (tid < 64) Bl[tid] = Bv[h * 64 + tid];
    else if (tid < 128) SM[5][tid - 64] = packhl(Cv[h * 64 + (tid - 64)]);
    __syncthreads();

    // ---- M1: S*S^T -> D~ = sd*acc (SM1), T0 = D~ + I (SM2) ----
    mm64<4>(SM[0], SM[0], SM[1], SM[2], nullptr, nullptr, sd, 0.f, tid);
    __syncthreads();
    // ---- Horner (T_i all symmetric): T1, T2, T3 = T ----
    mm64<1>(SM[1], SM[2], SM[3], nullptr, nullptr, nullptr, 0.f, 0.f, tid);
    __syncthreads();
    mm64<1>(SM[1], SM[3], SM[2], nullptr, nullptr, nullptr, 0.f, 0.f, tid);
    __syncthreads();
    mm64<1>(SM[1], SM[2], SM[3], nullptr, nullptr, nullptr, 0.f, 0.f, tid);
    __syncthreads();
    // ---- M5: SH = S*T; X = c1*T + c2*SH - I (SM2), XT = c1*T - c2*SH - I (SM1) ----
    mm64<5>(SM[0], SM[3], SM[2], SM[1], nullptr, SM[3], c1, c2, tid);
    __syncthreads();

    // ---- seed: Vt row0 = dB = (dt/2)(X*B + B) ----
    if (w == 0) {
        const unsigned* Xr = SM[2] + lane * STRU;
        float acc = 0.0f;
        #pragma unroll
        for (int m4 = 0; m4 < 16; ++m4) {
            uint4 xv = *(const uint4*)(Xr + 4 * m4);
            float4 b4 = *(const float4*)&Bl[4 * m4];
            acc += unpackf(xv.x) * b4.x + unpackf(xv.y) * b4.y
                 + unpackf(xv.z) * b4.z + unpackf(xv.w) * b4.w;
        }
        SM[4][lane] = packhl(c * (acc + Bl[lane]));
    }
    __syncthreads();

    // ---- ladder A: s=0..5: dual-square X -> X^2, X^2T; double Vt with X ----
    unsigned *bX = SM[2], *bXT = SM[1], *bN = SM[0], *bNT = SM[3];
    #pragma unroll 1
    for (int s = 0; s < 6; ++s) {
        mm64<3>(bX, bXT, bN, bNT, nullptr, nullptr, 0.f, 0.f, tid);
        dbl64(SM[4], bX, 1 << s, tid);
        __syncthreads();
        unsigned* t0 = bX;  bX  = bN;  bN  = t0;
        t0 = bXT; bXT = bNT; bNT = t0;
    }
    // bX = E = dA^64, bXT = E^T

    // ---- ladder B: s=0..5: double Ut with XT = (E^T)^(2^s); dual-square (s<5) ----
    #pragma unroll 1
    for (int s = 0; s < 6; ++s) {
        if (s < 5) mm64<3>(bX, bXT, bN, bNT, nullptr, nullptr, 0.f, 0.f, tid);
        dbl64(SM[5], bXT, 1 << s, tid);
        __syncthreads();
        if (s < 5) {
            unsigned* t0 = bX;  bX  = bN;  bN  = t0;
            t0 = bXT; bXT = bNT; bNT = t0;
        }
    }

    // ---- final: out[h][64q + r] = sum_n Ut[q][n] * Vt[r][n] ----
    mm64<2>(SM[5], SM[4], nullptr, nullptr, out + (size_t)h * 4096, nullptr,
            0.f, 0.f, tid);
}

extern "C" void kernel_launch(void* const* d_in, const int* in_sizes, int n_in,
                              void* d_out, int out_size, void* d_ws, size_t ws_size,
                              hipStream_t stream) {
    const float* A  = (const float*)d_in[0];
    const float* B  = (const float*)d_in[1];
    const float* C  = (const float*)d_in[2];
    const float* ld = (const float*)d_in[3];
    float* out = (float*)d_out;
    const int H = in_sizes[3];   // 256 heads
    krylov_kernel<<<H, 512, 0, stream>>>(A, B, C, ld, out);
}